// Round 7
// baseline (103.128 us; speedup 1.0000x reference)
//
#include <hip/hip_runtime.h>
#include <hip/hip_bf16.h>

#define D_S 128

typedef short bf16x8 __attribute__((ext_vector_type(8)));
typedef float f32x4 __attribute__((ext_vector_type(4)));

__device__ __forceinline__ unsigned short f32_to_bf16(float f) {
  unsigned int u = __float_as_uint(f);
  return (unsigned short)((u + 0x7FFFu + ((u >> 16) & 1u)) >> 16);  // RN-even
}
__device__ __forceinline__ unsigned int pack2_bf16(float lo, float hi) {
  return (unsigned int)f32_to_bf16(lo) | ((unsigned int)f32_to_bf16(hi) << 16);
}
__device__ __forceinline__ bf16x8 cvt_frag(float4 x, float4 y) {
  union { bf16x8 v; unsigned int u[4]; } r;
  r.u[0] = pack2_bf16(x.x, x.y);
  r.u[1] = pack2_bf16(x.z, x.w);
  r.u[2] = pack2_bf16(y.x, y.y);
  r.u[3] = pack2_bf16(y.z, y.w);
  return r.v;
}

// ---------------------------------------------------------------------------
// Kernel 1 (MFMA, LDS-staged): computes AB[n][j] = Wc[j].s[n] (+b1, j<128)
// and writes it in the XCD-SLICED layout:
//   Atab[(sl*N + n)*16 + i] = AB[n][sl*16 + i]        (A half, k in [0,128))
//   Btab[(sl*N + n)*16 + i] = AB[n][128 + sl*16 + i]  (B half)
// Block = 256 thr (4 waves), tile 64 nodes x 256 j, K=128.
// s staged coalesced into XOR-swizzled LDS ((row&7)<<4 on byte addr: 8-way
// read spread = LDS floor for 64x16B). R6 bug: direct A-frag loads touched
// 32 half-used cache lines per instruction. B-frags from W1 fp32 (L2-hot)
// with in-register cvt (kills the separate w1cvt launch from R6).
// D layout (m89-verified): col=lane&15, row=(lane>>4)*4+reg.
// ---------------------------------------------------------------------------
__global__ __launch_bounds__(256) void precompute_mfma(
    const float* __restrict__ s, const float* __restrict__ W1,
    const float* __restrict__ b1, unsigned short* __restrict__ Atab,
    unsigned short* __restrict__ Btab, int n_nodes) {
  __shared__ __align__(16) unsigned short s_tile[64 * 128];  // 16 KB, swizzled
  __shared__ __align__(16) unsigned short o_tile[64 * 256];  // 32 KB, swizzled
  int t = threadIdx.x;
  int wv = t >> 6, lane = t & 63;
  int lr = lane & 15, lc = lane >> 4;
  int n0 = blockIdx.x * 64;

  // ---- stage s: 64 rows x 128 f32 -> bf16 LDS (coalesced 32B/thread) ----
#pragma unroll
  for (int rep = 0; rep < 4; ++rep) {
    int idx = t + rep * 256;  // 1024 chunks of 8 floats
    int row = idx >> 4;
    int c8 = (idx & 15) * 8;
    int gn = n0 + row;
    if (gn > n_nodes - 1) gn = n_nodes - 1;  // clamp; masked at store
    const float* sp = s + (size_t)gn * D_S + c8;
    float4 x = *(const float4*)sp;
    float4 y = *(const float4*)(sp + 4);
    bf16x8 pk = cvt_frag(x, y);
    int byte = (row * 256 + c8 * 2) ^ ((row & 7) << 4);
    *(bf16x8*)((char*)s_tile + byte) = pk;
  }
  __syncthreads();

  // ---- A fragments from LDS (8-way spread = floor) ----
  bf16x8 afrag[4][4];
#pragma unroll
  for (int m = 0; m < 4; ++m) {
    int row = m * 16 + lr;
    int swz = (row & 7) << 4;
#pragma unroll
    for (int ks = 0; ks < 4; ++ks) {
      int byte = (row * 256 + lc * 16 + ks * 64) ^ swz;
      afrag[m][ks] = *(const bf16x8*)((const char*)s_tile + byte);
    }
  }

#pragma unroll 1
  for (int chunk = 0; chunk < 2; ++chunk) {
    // B fragments: Wc row j = chunk*128 + wv*32 + nt*16 + lr
    //   -> W1[j'][chunk*128 + k], j' = j - chunk*128.
    bf16x8 bfr[2][4];
#pragma unroll
    for (int nt = 0; nt < 2; ++nt) {
      const float* wrow =
          W1 + (size_t)(wv * 32 + nt * 16 + lr) * (2 * D_S) + chunk * D_S + lc * 8;
#pragma unroll
      for (int ks = 0; ks < 4; ++ks) {
        float4 x = *(const float4*)(wrow + ks * 32);
        float4 y = *(const float4*)(wrow + ks * 32 + 4);
        bfr[nt][ks] = cvt_frag(x, y);
      }
    }

    f32x4 acc[4][2] = {};
#pragma unroll
    for (int ks = 0; ks < 4; ++ks)
#pragma unroll
      for (int m = 0; m < 4; ++m)
#pragma unroll
        for (int nt = 0; nt < 2; ++nt)
          acc[m][nt] = __builtin_amdgcn_mfma_f32_16x16x32_bf16(
              afrag[m][ks], bfr[nt][ks], acc[m][nt], 0, 0, 0);

    if (chunk == 0) {  // bias on the A half
#pragma unroll
      for (int nt = 0; nt < 2; ++nt) {
        float bv = b1[wv * 32 + nt * 16 + lr];
#pragma unroll
        for (int m = 0; m < 4; ++m)
#pragma unroll
          for (int r = 0; r < 4; ++r) acc[m][nt][r] += bv;
      }
    }

    // pack D -> o_tile (2B elements, swizzled; 2-lane/dword aliasing = free)
#pragma unroll
    for (int m = 0; m < 4; ++m)
#pragma unroll
      for (int nt = 0; nt < 2; ++nt) {
        int col = chunk * 128 + wv * 32 + nt * 16 + lr;
#pragma unroll
        for (int r = 0; r < 4; ++r) {
          int row = m * 16 + lc * 4 + r;
          int byte = (row * 512 + col * 2) ^ ((row & 7) << 4);
          *(unsigned short*)((char*)o_tile + byte) = f32_to_bf16(acc[m][nt][r]);
        }
      }
  }
  __syncthreads();

  // ---- store sliced records: wave w covers slice rep*4+w, lane = node ----
#pragma unroll
  for (int rep = 0; rep < 2; ++rep) {
    int idx = t + rep * 256;  // 512 = 8 slices x 64 nodes
    int sl = idx >> 6, node = idx & 63;
    int gn = n0 + node;
    if (gn < n_nodes) {
      int sw = (node & 7) << 4;
      int base = node * 512 + sl * 32;
      uint4 ra0 = *(const uint4*)((const char*)o_tile + ((base) ^ sw));
      uint4 ra1 = *(const uint4*)((const char*)o_tile + ((base + 16) ^ sw));
      uint4 rb0 = *(const uint4*)((const char*)o_tile + ((base + 256) ^ sw));
      uint4 rb1 = *(const uint4*)((const char*)o_tile + ((base + 256 + 16) ^ sw));
      size_t rec = ((size_t)sl * n_nodes + gn) << 4;
      *(uint4*)(Atab + rec) = ra0;
      *(uint4*)(Atab + rec + 8) = ra1;
      *(uint4*)(Btab + rec) = rb0;
      *(uint4*)(Btab + rec + 8) = rb1;
    }
  }
}

// ---------------------------------------------------------------------------
// Kernel 2: XCD-sliced edge gather. slice = blockIdx%8 -> under round-robin
// dispatch all blocks of a slice land on one XCD, whose L2 then holds that
// slice's 3.2 MB (Atab+Btab slice) -> gathers are L2-hits instead of the
// L3/fabric path that pinned R4-R6 at ~53us. Index reads and partial stores
// are non-temporal so the 6.4 MB index stream doesn't evict the table.
//   P[sl][e] = sum_{i<16} W2[sl*16+i] * silu(A[row][sl*16+i]+B[col][sl*16+i])
// ---------------------------------------------------------------------------
__device__ __forceinline__ float silu2(unsigned int ua, unsigned int ub,
                                       float wlo, float whi) {
  float h0 = __uint_as_float(ua << 16) + __uint_as_float(ub << 16);
  float h1 = __uint_as_float(ua & 0xFFFF0000u) + __uint_as_float(ub & 0xFFFF0000u);
  float e0 = __builtin_amdgcn_exp2f(h0 * -1.442695041f);
  float e1 = __builtin_amdgcn_exp2f(h1 * -1.442695041f);
  float r0 = __builtin_amdgcn_rcpf(1.f + e0);
  float r1 = __builtin_amdgcn_rcpf(1.f + e1);
  return h0 * r0 * wlo + h1 * r1 * whi;
}

__global__ __launch_bounds__(256) void edge_sliced(
    const int* __restrict__ ei, const unsigned short* __restrict__ Atab,
    const unsigned short* __restrict__ Btab, const float* __restrict__ W2,
    float* __restrict__ P, int E, int N) {
  int bid = blockIdx.x;
  int slice = bid & 7;
  int e = (bid >> 3) * 256 + threadIdx.x;
  if (e >= E) return;

  int row = __builtin_nontemporal_load(ei + e);
  int col = __builtin_nontemporal_load(ei + E + e);

  const uint4* pa = (const uint4*)(Atab + (((size_t)slice * N + row) << 4));
  const uint4* pb = (const uint4*)(Btab + (((size_t)slice * N + col) << 4));
  uint4 a0 = pa[0], a1 = pa[1];
  uint4 b0 = pb[0], b1v = pb[1];

  const float* w = W2 + (slice << 4);  // block-uniform -> scalar loads
  float p = 0.f;
  p += silu2(a0.x, b0.x, w[0], w[1]);
  p += silu2(a0.y, b0.y, w[2], w[3]);
  p += silu2(a0.z, b0.z, w[4], w[5]);
  p += silu2(a0.w, b0.w, w[6], w[7]);
  p += silu2(a1.x, b1v.x, w[8], w[9]);
  p += silu2(a1.y, b1v.y, w[10], w[11]);
  p += silu2(a1.z, b1v.z, w[12], w[13]);
  p += silu2(a1.w, b1v.w, w[14], w[15]);

  __builtin_nontemporal_store(p, P + (size_t)slice * E + e);
}

// ---------------------------------------------------------------------------
// Kernel 3: out[e] = b2 + sum_{sl=0..7} P[sl][e]  (fixed order: deterministic)
// ---------------------------------------------------------------------------
__global__ __launch_bounds__(256) void combine(
    const float* __restrict__ P, const float* __restrict__ b2,
    float* __restrict__ out, int E) {
  int e = blockIdx.x * 256 + threadIdx.x;
  if (e >= E) return;
  float v = b2[0];
#pragma unroll
  for (int k = 0; k < 8; ++k)
    v += __builtin_nontemporal_load(P + (size_t)k * E + e);
  out[e] = v;
}

// ---------------------------------------------------------------------------
// Fallback (workspace too small): direct per-edge compute, fp32.
// ---------------------------------------------------------------------------
__global__ __launch_bounds__(256) void edge_direct(
    const float* __restrict__ s, const int* __restrict__ ei,
    const float* __restrict__ W1, const float* __restrict__ b1,
    const float* __restrict__ W2, const float* __restrict__ b2,
    float* __restrict__ out, int E) {
  __shared__ float sh[256];
  __shared__ float red[128];
  int e = blockIdx.x;
  int t = threadIdx.x;
  int row = ei[e], col = ei[E + e];
  sh[t] = (t < 128) ? s[(size_t)row * D_S + t] : s[(size_t)col * D_S + (t - 128)];
  __syncthreads();
  if (t < 128) {
    float acc = b1[t];
    const float* w = W1 + (size_t)t * 256;
#pragma unroll 8
    for (int jj = 0; jj < 256; ++jj) acc += sh[jj] * w[jj];
    red[t] = (acc / (1.f + __expf(-acc))) * W2[t];
  }
  __syncthreads();
  if (t < 64) {
    float x = red[t] + red[t + 64];
#pragma unroll
    for (int off = 32; off; off >>= 1) x += __shfl_xor(x, off, 64);
    if (t == 0) out[e] = x + b2[0];
  }
}

extern "C" void kernel_launch(void* const* d_in, const int* in_sizes, int n_in,
                              void* d_out, int out_size, void* d_ws, size_t ws_size,
                              hipStream_t stream) {
  const float* s  = (const float*)d_in[0];
  const int*   ei = (const int*)d_in[1];
  const float* W1 = (const float*)d_in[2];
  const float* b1 = (const float*)d_in[3];
  const float* W2 = (const float*)d_in[4];
  const float* b2 = (const float*)d_in[5];
  float* out = (float*)d_out;

  int n_nodes = in_sizes[0] / D_S;
  int E = in_sizes[1] / 2;

  size_t tab_elems = (size_t)8 * n_nodes * 16;              // per table, ushort
  size_t need = 2 * tab_elems * sizeof(unsigned short) +    // Atab + Btab
                (size_t)8 * E * sizeof(float);              // P partials
  if (ws_size >= need) {
    unsigned short* Atab = (unsigned short*)d_ws;
    unsigned short* Btab = Atab + tab_elems;
    float* P = (float*)(Btab + tab_elems);
    precompute_mfma<<<(n_nodes + 63) / 64, 256, 0, stream>>>(s, W1, b1, Atab,
                                                             Btab, n_nodes);
    int nchunk = (E + 255) / 256;
    edge_sliced<<<nchunk * 8, 256, 0, stream>>>(ei, Atab, Btab, W2, P, E,
                                                n_nodes);
    combine<<<nchunk, 256, 0, stream>>>(P, b2, out, E);
  } else {
    edge_direct<<<E, 256, 0, stream>>>(s, ei, W1, b1, W2, b2, out, E);
  }
}